// Round 8
// baseline (481.427 us; speedup 1.0000x reference)
//
#include <hip/hip_runtime.h>

#define T_STEPS 256
#define B_COLS  65536u
#define GAMMA_F 0.99f

#define CHUNK   16                    // rows per thread (exactness proven: chunk
#define NCH     (T_STEPS / CHUNK)     //   w/ >=1 reset -> bit-exact; 6^-16/chunk)
#define XT      32                    // col-quads per block (128 cols)
#define CPT     4                     // float4 lanes

// EXACT segmented affine scan (no warm-up redundancy), float4, 50% occupancy.
//
// Round-8 rationale: useful-byte service rate was ~2.0 TB/s in ALL prior
// rounds once spill traffic is excluded; R2's total TCC rate (2.76 TB/s incl.
// spills) proves the fabric can go higher with more requests in flight.
// The untested corner is float4 + max clean resident waves + minimal bytes:
// 4096 waves (16/CU, 50% occ), zero warm-up bytes, zero spills.
//
// Step i (i = T-2..0):  ret = acc*Dg + r ; out[i] = (ret - v)^2 ;
//                       acc = l ? tv : ret ;  Dg = discount[i+1]*gamma
//                       l = (step_type[i]==2) | (rollout_b|train_b) (i>0)
// Phase 1: per-thread 16-row chunk -> affine (alpha, beta); Dg held in regs
//          (64 VGPR), R/TV streamed in 2-row groups (consumed immediately).
// Phase 1d: 16-step serial scan per column in LDS (y==0 threads).
// Phase 2: exact replay; Dg from regs, R/TV re-streamed (L2/L3), V fresh.
// Flags are single-read -> nontemporal loads (don't evict twice-read floats
// from L3). Output single-write -> nontemporal stores.
// Register budget pinned to 128 via amdgpu_waves_per_eu(4,4) so the allocator
// neither spills (R2/R4 failure) nor over-allocates (would halve occupancy).

typedef float f32x4 __attribute__((ext_vector_type(4)));
typedef int   i32x4 __attribute__((ext_vector_type(4)));

__device__ __forceinline__ float4 ld4f(const float* __restrict__ p, unsigned idx) {
    return *reinterpret_cast<const float4*>(p + idx);
}
__device__ __forceinline__ i32x4 ld4i_nt(const int* __restrict__ p, unsigned idx) {
    return __builtin_nontemporal_load(reinterpret_cast<const i32x4*>(p + idx));
}

__global__ __launch_bounds__(512)
__attribute__((amdgpu_waves_per_eu(4, 4)))
void td_loss_kernel(
    const float* __restrict__ reward,
    const float* __restrict__ discount,
    const float* __restrict__ value,
    const float* __restrict__ target_value,
    const int*   __restrict__ step_type,
    const int*   __restrict__ rollout_b,
    const int*   __restrict__ train_b,
    float*       __restrict__ out)
{
    const int x  = threadIdx.x;                            // 0..31 (col-quad)
    const int ch = threadIdx.y;                            // 0..15 (chunk)
    const unsigned col  = (blockIdx.x * XT + x) * CPT;
    const int      hi   = ch * CHUNK + (CHUNK - 1);        // top row of chunk
    const unsigned base = (unsigned)hi * B_COLS + col;
    // j = 0..15  <=>  row i = hi - j (application order, high->low)

    __shared__ float4 s_al[NCH][XT];
    __shared__ float4 s_be[NCH][XT];
    __shared__ float4 s_ac[NCH][XT];

    // ---- Phase 1a: reset masks from nontemporal int4 loads.
    unsigned msk[4] = {0u, 0u, 0u, 0u};
#pragma unroll
    for (int j = 0; j < CHUNK; ++j) {
        const i32x4 s = ld4i_nt(step_type, base - (unsigned)j * B_COLS);
        msk[0] |= (unsigned)(s.x == 2) << j;
        msk[1] |= (unsigned)(s.y == 2) << j;
        msk[2] |= (unsigned)(s.z == 2) << j;
        msk[3] |= (unsigned)(s.w == 2) << j;
    }
#pragma unroll
    for (int j = 0; j < CHUNK; ++j) {
        const i32x4 s = ld4i_nt(rollout_b, base - (unsigned)j * B_COLS);
        msk[0] |= (unsigned)(s.x != 0) << j;
        msk[1] |= (unsigned)(s.y != 0) << j;
        msk[2] |= (unsigned)(s.z != 0) << j;
        msk[3] |= (unsigned)(s.w != 0) << j;
    }
#pragma unroll
    for (int j = 0; j < CHUNK; ++j) {
        const i32x4 s = ld4i_nt(train_b, base - (unsigned)j * B_COLS);
        msk[0] |= (unsigned)(s.x != 0) << j;
        msk[1] |= (unsigned)(s.y != 0) << j;
        msk[2] |= (unsigned)(s.z != 0) << j;
        msk[3] |= (unsigned)(s.w != 0) << j;
    }
    // i = T-1: forced reset (acc := tv[T-1]); out[T-1] = 0.
    if (ch == NCH - 1) { msk[0] |= 1u; msk[1] |= 1u; msk[2] |= 1u; msk[3] |= 1u; }
    // (i = 0: reference forces b[0]=False, but that flag only affects acc AFTER
    //  out[0] is written, and that acc is never consumed -> no special case.)

    // ---- Phase 1b/c: Dg held in registers (16 float4); R/TV streamed 2 rows
    // at a time, consumed immediately into (alpha, beta).
    float4 Dg[CHUNK];
    float al[4] = {1.f, 1.f, 1.f, 1.f};
    float be[4] = {0.f, 0.f, 0.f, 0.f};
#pragma unroll
    for (int h = 0; h < CHUNK / 2; ++h) {
        float4 Rt[2], Tt[2];
#pragma unroll
        for (int jj = 0; jj < 2; ++jj) {
            const int j = 2 * h + jj;
            const unsigned idx  = base - (unsigned)j * B_COLS;
            const unsigned idx1 = (hi - j == T_STEPS - 1) ? idx : idx + B_COLS;
            float4 d = ld4f(discount, idx1);
            d.x *= GAMMA_F; d.y *= GAMMA_F; d.z *= GAMMA_F; d.w *= GAMMA_F;
            Dg[j]  = d;                     // persists into phase 2
            Rt[jj] = ld4f(reward, idx1);
            Tt[jj] = ld4f(target_value, idx);
        }
#pragma unroll
        for (int jj = 0; jj < 2; ++jj) {
            const int j = 2 * h + jj;
            const float* Dv = reinterpret_cast<const float*>(&Dg[j]);
            const float* Rv = reinterpret_cast<const float*>(&Rt[jj]);
            const float* Tv = reinterpret_cast<const float*>(&Tt[jj]);
#pragma unroll
            for (int k = 0; k < 4; ++k) {
                const bool  l = (msk[k] >> j) & 1u;
                const float g = l ? 0.0f : Dv[k];
                const float o = l ? Tv[k] : Rv[k];
                be[k] = fmaf(g, be[k], o);   // identical rounding to sequential
                al[k] *= g;                  // collapses to 0 at first reset
            }
        }
    }
    s_al[ch][x] = make_float4(al[0], al[1], al[2], al[3]);
    s_be[ch][x] = make_float4(be[0], be[1], be[2], be[3]);
    __syncthreads();

    // ---- Phase 1d: 16-step serial scan per column (y==0 threads, 4 cols each).
    if (ch == 0) {
        float a0 = 0.f, a1 = 0.f, a2 = 0.f, a3 = 0.f;   // chunk 15: forced reset
#pragma unroll
        for (int k = NCH - 1; k >= 0; --k) {
            s_ac[k][x] = make_float4(a0, a1, a2, a3);   // acc entering chunk k
            const float4 A  = s_al[k][x];
            const float4 Bv = s_be[k][x];
            a0 = fmaf(A.x, a0, Bv.x);
            a1 = fmaf(A.y, a1, Bv.y);
            a2 = fmaf(A.z, a2, Bv.z);
            a3 = fmaf(A.w, a3, Bv.w);
        }
    }
    __syncthreads();

    // ---- Phase 2: exact replay. Dg from regs; R/TV re-streamed; V fresh.
    const float4 a0v = s_ac[ch][x];
    float ac[4] = {a0v.x, a0v.y, a0v.z, a0v.w};
#pragma unroll
    for (int h = 0; h < CHUNK / 2; ++h) {
        float4 Rt[2], Tt[2], Vt[2];
#pragma unroll
        for (int jj = 0; jj < 2; ++jj) {
            const int j = 2 * h + jj;
            const unsigned idx  = base - (unsigned)j * B_COLS;
            const unsigned idx1 = (hi - j == T_STEPS - 1) ? idx : idx + B_COLS;
            Rt[jj] = ld4f(reward, idx1);
            Tt[jj] = ld4f(target_value, idx);
            Vt[jj] = ld4f(value, idx);
        }
#pragma unroll
        for (int jj = 0; jj < 2; ++jj) {
            const int  j   = 2 * h + jj;
            const bool top = (hi - j == T_STEPS - 1);
            const unsigned idx = base - (unsigned)j * B_COLS;
            const float* Dv = reinterpret_cast<const float*>(&Dg[j]);
            const float* Rv = reinterpret_cast<const float*>(&Rt[jj]);
            const float* Tv = reinterpret_cast<const float*>(&Tt[jj]);
            const float* Vv = reinterpret_cast<const float*>(&Vt[jj]);
            float o[4];
#pragma unroll
            for (int k = 0; k < 4; ++k) {
                const float ret = fmaf(ac[k], Dv[k], Rv[k]);
                const bool  l   = ((msk[k] >> j) & 1u) | top;
                ac[k] = l ? Tv[k] : ret;
                const float df = ret - Vv[k];
                o[k] = df * df;
            }
            f32x4 ov;
            if (top) { ov = (f32x4)(0.f); }            // out[T-1] = 0
            else     { ov.x = o[0]; ov.y = o[1]; ov.z = o[2]; ov.w = o[3]; }
            __builtin_nontemporal_store(ov, reinterpret_cast<f32x4*>(out + idx));
        }
    }
}

extern "C" void kernel_launch(void* const* d_in, const int* in_sizes, int n_in,
                              void* d_out, int out_size, void* d_ws, size_t ws_size,
                              hipStream_t stream) {
    const float* reward       = (const float*)d_in[0];
    const float* discount     = (const float*)d_in[1];
    const float* value        = (const float*)d_in[2];
    const float* target_value = (const float*)d_in[3];
    const int*   step_type    = (const int*)d_in[4];
    const int*   rollout_b    = (const int*)d_in[5];
    const int*   train_b      = (const int*)d_in[6];
    float*       out          = (float*)d_out;

    dim3 block(XT, NCH);                    // (32,16) = 512 threads = 8 waves
    dim3 grid(B_COLS / (XT * CPT));         // 512 blocks; 2/CU resident
    td_loss_kernel<<<grid, block, 0, stream>>>(
        reward, discount, value, target_value, step_type, rollout_b, train_b, out);
}